// Round 3
// baseline (372.576 us; speedup 1.0000x reference)
//
#include <hip/hip_runtime.h>
#include <hip/hip_bf16.h>

typedef unsigned short ushort_t;
typedef __attribute__((ext_vector_type(8))) short short8;
typedef __attribute__((ext_vector_type(4))) float f32x4;

#define NCOMP    8
#define CIN      512
#define COUT     256
#define H        64
#define HP       66                 // padded spatial dim (halo 1 each side)
#define PLANE    (HP * HP)          // 4356 px per (b, cc) plane
#define PLANE_EL (PLANE * 8)        // 34848 ushorts per plane
#define KSTRIDE  (4 * PLANE_EL)     // B-pointer advance per 32-ic K-step
#define OHW      128
#define NB       8

// Cayley-Dickson |comp| table for n=8 (verified rounds 1-2); sign(i,j)=+1 iff i>=j.
__device__ const int d_idx8[8][8] = {
    {0,1,2,1,4,3,2,3},
    {1,0,3,2,5,4,1,2},
    {2,1,0,1,6,5,4,3},
    {3,2,1,0,7,6,5,4},
    {4,3,2,3,0,1,2,1},
    {5,4,1,2,1,0,3,2},
    {6,5,4,3,2,1,0,1},
    {7,6,5,4,3,2,1,0}};

// Tap tables: output parity p, tap a: kernel index kh, input offset dh (ih = ohh + dh).
__device__ const int kh_tab[2][2] = {{1,3},{0,2}};
__device__ const int dh_tab[2][2] = {{0,-1},{1,0}};

// ---------------- fused prep: x->NHWC-c8 bf16 (+halo zero), weights, bias ----
// Roles by blockIdx.x:
//   [0,4096)      x transpose: (b, ih, ccg) -> 64ic x 64iw tile
//   [4096,4608)   halo zero: one (b,cc) plane's 260 halo pixels
//   [4608,12800)  Abf build (2M elems)
//   12800         fused bias
__global__ void prep_all(const float* __restrict__ x, const float* __restrict__ W,
                         const float* __restrict__ bias,
                         ushort_t* __restrict__ xpadT, ushort_t* __restrict__ Abf,
                         float* __restrict__ bbig) {
    __shared__ ushort_t tile[64 * 66];
    const int q = blockIdx.x;
    const int t = threadIdx.x;

    if (q < 4096) {
        const int b   = q & 7;
        const int ih  = (q >> 3) & 63;
        const int ccg = q >> 9;          // 0..7, covers ic [ccg*64, ccg*64+64)
        // phase 1: coalesced 256B row reads, contiguous LDS writes
#pragma unroll
        for (int i = 0; i < 16; ++i) {
            int e = i * 256 + t;         // 0..4095
            int ic_l = e >> 6, iw = e & 63;
            float v = x[(((size_t)b * CIN + ccg * 64 + ic_l) * H + ih) * H + iw];
            __hip_bfloat16 h = __float2bfloat16(v);
            tile[ic_l * 66 + iw] = *(ushort_t*)&h;
        }
        __syncthreads();
        // phase 2: gather 8 ic per pixel, contiguous 16B/lane global stores
#pragma unroll
        for (int r = 0; r < 2; ++r) {
            int q2 = r * 256 + t;        // 0..511
            int cc_l = q2 >> 6, iw = q2 & 63;
            ushort_t us[8];
#pragma unroll
            for (int j = 0; j < 8; ++j) us[j] = tile[(cc_l * 8 + j) * 66 + iw];
            uint4 v;
            v.x = (unsigned)us[0] | ((unsigned)us[1] << 16);
            v.y = (unsigned)us[2] | ((unsigned)us[3] << 16);
            v.z = (unsigned)us[4] | ((unsigned)us[5] << 16);
            v.w = (unsigned)us[6] | ((unsigned)us[7] << 16);
            ushort_t* dst = xpadT + ((size_t)(b * 64 + ccg * 8 + cc_l) * PLANE
                                     + (ih + 1) * HP + (iw + 1)) * 8;
            *(uint4*)dst = v;
        }
    } else if (q < 4608) {
        const int p = q - 4096;
        ushort_t* base = xpadT + (size_t)p * PLANE_EL;   // plane (b*64+cc)
        if (t < 260) {
            int ihp, iwp;
            if      (t < 66)  { ihp = 0;           iwp = t; }
            else if (t < 132) { ihp = HP - 1;      iwp = t - 66; }
            else if (t < 196) { ihp = t - 132 + 1; iwp = 0; }
            else              { ihp = t - 196 + 1; iwp = HP - 1; }
            *(uint4*)(base + (ihp * HP + iwp) * 8) = make_uint4(0, 0, 0, 0);
        }
    } else if (q < 12800) {
        const int gid = (q - 4608) * 256 + t;     // 0..2M-1
        int kin = gid & 31;
        int oc  = (gid >> 5) & 255;
        int ks  = (gid >> 13) & 63;
        int cls = gid >> 19;
        int k  = ks * 32 + kin;
        int a  = k >> 10, c = (k >> 9) & 1, ic = k & 511;
        int ph = cls >> 1, pw = cls & 1;
        int kh = kh_tab[ph][a], kw = kh_tab[pw][c];
        int i = oc >> 5, co = oc & 31;
        int j = ic >> 6, ci = ic & 63;
        float s = (i >= j) ? 1.0f : -1.0f;
        float v = s * W[(((size_t)(d_idx8[i][j] * 64 + ci) * 32 + co) * 4 + kh) * 4 + kw];
        __hip_bfloat16 h = __float2bfloat16(v);
        Abf[gid] = *(ushort_t*)&h;
    } else {
        if (t < COUT) {
            int i = t >> 5, co = t & 31;
            float acc = 0.0f;
            for (int j = 0; j < NCOMP; ++j)
                acc += ((i >= j) ? 1.0f : -1.0f) * bias[d_idx8[i][j] * 32 + co];
            bbig[t] = acc;
        }
    }
}

// ---------------- main: implicit-GEMM MFMA (unchanged structure) ----------------
__device__ __forceinline__ void async16(void* lds_dst, const void* g_src) {
    __builtin_amdgcn_global_load_lds(
        (const __attribute__((address_space(1))) unsigned int*)g_src,
        (__attribute__((address_space(3))) unsigned int*)lds_dst,
        16, 0, 0);
}

__launch_bounds__(256)
__global__ void htconv_mfma(const ushort_t* __restrict__ xpadT,
                            const ushort_t* __restrict__ Abf,
                            const float* __restrict__ bbig,
                            float* __restrict__ out) {
    __shared__ __align__(16) ushort_t smem[8192];
    char* sb = (char*)smem;

    const int t     = threadIdx.x;            // 0..255
    const int ntile = blockIdx.x;             // 0..31 -> ohh0 = 2*ntile
    const int mtile = blockIdx.y;             // 0..1
    const int cls   = blockIdx.z & 3;
    const int b     = blockIdx.z >> 2;
    const int ph = cls >> 1, pw = cls & 1;
    const int ohh0 = ntile * 2;

    // ---- staging addresses ----
    const int swz  = (t & 3) ^ ((t >> 3) & 3);          // swizzled k-chunk 0..3
    const int m_a  = t >> 2;                            // A row 0..63 within half-tile
    const ushort_t* ap = Abf + (((size_t)cls * 64) * 256 + (size_t)mtile * 128 + m_a) * 32 + swz * 8;

    const int dh0 = dh_tab[ph][0], dh1 = dh_tab[ph][1];
    const int dw0 = dh_tab[pw][0], dw1 = dh_tab[pw][1];
    const int oww = t >> 2;                             // pixel col 0..63
    const ushort_t* bp[2][2][2];
#pragma unroll
    for (int a = 0; a < 2; ++a) {
        int dh = (a == 0) ? dh0 : dh1;
#pragma unroll
        for (int c = 0; c < 2; ++c) {
            int dw = (c == 0) ? dw0 : dw1;
#pragma unroll
            for (int row = 0; row < 2; ++row) {
                size_t idx = ((size_t)(b * 64 + swz) * PLANE
                              + (ohh0 + row + dh + 1) * HP + (oww + dw + 1)) * 8;
                bp[a][c][row] = xpadT + idx;
            }
        }
    }

    // ---- fragment read offsets ----
    const int lane = t & 63, wave = t >> 6;
    const int wm = wave >> 1, wn = wave & 1;
    const int col = lane & 15, quad = lane >> 4;
    const int soff = (quad ^ ((col >> 1) & 3)) * 16;    // bytes
    const int aoff = (wm * 64 + col) * 64 + soff;       // bytes into A region
    const int boff = 8192 + (wn * 64 + col) * 64 + soff;

    f32x4 acc[4][4];
#pragma unroll
    for (int i = 0; i < 4; ++i)
#pragma unroll
        for (int j = 0; j < 4; ++j)
            acc[i][j] = (f32x4){0.f, 0.f, 0.f, 0.f};

    // ---- K loop ----
#pragma unroll
    for (int a = 0; a < 2; ++a) {
#pragma unroll
        for (int c = 0; c < 2; ++c) {
            const ushort_t* b0 = bp[a][c][0];
            const ushort_t* b1 = bp[a][c][1];
            for (int kk = 0; kk < 16; ++kk) {
                async16(sb + t * 16,         ap);
                async16(sb + 4096 + t * 16,  ap + 2048);
                async16(sb + 8192 + t * 16,  b0);
                async16(sb + 12288 + t * 16, b1);
                ap += 8192; b0 += KSTRIDE; b1 += KSTRIDE;
                __syncthreads();

                short8 af[4], bf[4];
#pragma unroll
                for (int s = 0; s < 4; ++s) {
                    af[s] = *(const short8*)(sb + aoff + s * 1024);
                    bf[s] = *(const short8*)(sb + boff + s * 1024);
                }
#pragma unroll
                for (int sm = 0; sm < 4; ++sm)
#pragma unroll
                    for (int sn = 0; sn < 4; ++sn)
                        acc[sm][sn] = __builtin_amdgcn_mfma_f32_16x16x32_bf16(
                            af[sm], bf[sn], acc[sm][sn], 0, 0, 0);
                __syncthreads();
            }
        }
    }

    // ---- epilogue: bias + stride-2 scatter store ----
    const int oh = 2 * (ohh0 + wn) + ph;
#pragma unroll
    for (int sm = 0; sm < 4; ++sm) {
#pragma unroll
        for (int r = 0; r < 4; ++r) {
            const int occ = mtile * 128 + wm * 64 + sm * 16 + quad * 4 + r;
            const float bv = bbig[occ];
            float* obase = out + (((size_t)b * COUT + occ) * OHW + oh) * OHW + pw;
#pragma unroll
            for (int sn = 0; sn < 4; ++sn) {
                const int owi = sn * 16 + col;
                obase[2 * owi] = acc[sm][sn][r] + bv;
            }
        }
    }
}

extern "C" void kernel_launch(void* const* d_in, const int* in_sizes, int n_in,
                              void* d_out, int out_size, void* d_ws, size_t ws_size,
                              hipStream_t stream) {
    const float* x    = (const float*)d_in[0];  // [8,512,64,64]
    const float* W    = (const float*)d_in[1];  // [8,64,32,4,4]
    const float* bias = (const float*)d_in[2];  // [8,32]
    float* out = (float*)d_out;                 // [8,256,128,128]

    ushort_t* xpadT = (ushort_t*)d_ws;                       // 8*64*66*66*8 = 17,842,176 elems
    ushort_t* Abf   = xpadT + (size_t)NB * 64 * PLANE_EL / 8;
    // (= xpadT + 8*64*PLANE*8 elems)
    Abf = xpadT + (size_t)NB * 64 * PLANE * 8;
    float* bbig = (float*)(Abf + (size_t)4 * 64 * 256 * 32);

    prep_all<<<dim3(12801), 256, 0, stream>>>(x, W, bias, xpadT, Abf, bbig);
    htconv_mfma<<<dim3(32, 2, 32), 256, 0, stream>>>(xpadT, Abf, bbig, out);
}